// Round 7
// baseline (128.979 us; speedup 1.0000x reference)
//
#include <hip/hip_runtime.h>
#include <math.h>

#define PSTR 33   // part[] col stride: 33 mod 32 = 1 -> lanes hit distinct banks

__device__ __forceinline__ float fast_atan2f(float y, float x) {
    float ax = fabsf(x), ay = fabsf(y);
    float mx = fmaxf(ax, ay);
    float mn = fminf(ax, ay);
    float a = mn * __builtin_amdgcn_rcpf(fmaxf(mx, 1e-30f));
    float s = a * a;
    float r = fmaf(s, fmaf(s, fmaf(s, fmaf(s, fmaf(s, -0.0117212f, 0.05265332f),
                    -0.11643287f), 0.19354346f), -0.33262347f), 0.99997726f) * a;
    r = (ay > ax) ? (1.57079637f - r) : r;
    r = (x < 0.0f) ? (3.14159274f - r) : r;
    return copysignf(r, y);
}

// 4 waves/patch: wave w owns rows [16w,16w+16) (+row 64 for wave 3). lane = column.
// Row-padded patch in LDS ([67][65], rows -1/65 replicated) -> NO shuffles, NO
// edge cases in the hot loop: xl/xr are plain per-lane ds_reads, xu/xd roll
// through registers. Register accumulators w/ compile-time window weights (R6).
__global__ __launch_bounds__(256, 6)
void sift_kernel(const float* __restrict__ in, float* __restrict__ out) {
    __shared__ float patch[67 * 65];   // 17.4 KB, padded row pr = r+1 (r in [-1,65])
    __shared__ float part[65 * PSTR];  // 8.6 KB  [column][sy*8 + a]
    __shared__ float gauss[65];

    const int tid  = threadIdx.x;
    const int lane = tid & 63;
    const int wid  = tid >> 6;
    const int m    = blockIdx.x;
    const int bc   = m >> 6;
    const int ij   = m & 63;
    const float* src = in + (size_t)bc * (520 * 520) + (ij >> 3) * (65 * 520) + (ij & 7) * 65;

    // ---- stage row-padded patch to LDS (rows clamped -> replicate pad) ----
    for (int k = tid; k < 67 * 65; k += 256) {
        int y = k / 65;
        int x = k - y * 65;
        int sy = y - 1; sy = (sy < 0) ? 0 : ((sy > 64) ? 64 : sy);
        patch[k] = src[sy * 520 + x];
    }
    // ---- zero partials ----
    for (int k = tid; k < 65 * PSTR; k += 256) part[k] = 0.0f;
    // ---- gaussian (wave 0): sigma = 65/sqrt(2) -> 2*sigma^2 = 4225 ----
    if (wid == 0) {
        float dd = (float)(lane - 32);
        float e  = __expf(-(dd * dd) * (1.0f / 4225.0f));
        float ssum = e;
        #pragma unroll
        for (int off = 32; off > 0; off >>= 1) ssum += __shfl_xor(ssum, off, 64);
        const float e64 = __expf(-1024.0f / 4225.0f);
        float inv = 1.0f / (ssum + e64);
        gauss[lane] = e * inv;
        if (lane == 0) gauss[64] = e64 * inv;
    }
    __syncthreads();

    const float GC = 0.5f * gauss[lane];   // column gaussian (0.5 grad scale folded)
    const int r0 = wid * 16;
    const int lm = (lane > 0) ? lane - 1 : 0;   // left col (replicate at 0)
    const int lp = lane + 1;                    // right col (col 64 is real data)

    float acc0[8], acc1[8], acc2[8];
    #pragma unroll
    for (int a = 0; a < 8; ++a) { acc0[a] = 0.0f; acc1[a] = 0.0f; acc2[a] = 0.0f; }

    // rolling rows: vA=row r-1, vB=row r, vC=row r+1 (padded indices r0..r0+2)
    float vA = patch[(r0    ) * 65 + lane];
    float vB = patch[(r0 + 1) * 65 + lane];
    float vC = patch[(r0 + 2) * 65 + lane];

    auto pixel = [&](int pr, float xu, float xd, float gw,
                     float W0, float W1, float W2, int mode) {
        float xl = patch[pr * 65 + lm];
        float xr = patch[pr * 65 + lp];
        float dx = xr - xl;
        float dy = xd - xu;
        float magw = sqrtf(fmaf(dx, dx, fmaf(dy, dy, 4e-10f))) * gw;
        float ang = fast_atan2f(dy, dx + 2e-10f);
        float o   = fmaf(ang, 1.27323954f, 8.0f);     // in (4,12]
        int bi = (int)o;
        float wo1 = o - (float)bi;
        int b0 = bi & 7;
        int b1 = (bi + 1) & 7;
        float q1 = wo1 * magw;
        float q0 = magw - q1;
        #pragma unroll
        for (int a = 0; a < 8; ++a) {
            float s = (a == b0) ? q0 : ((a == b1) ? q1 : 0.0f);
            if (mode == 0) {                 // k<=3: windows wid-1, wid
                acc0[a] = fmaf(s, W0, acc0[a]);
                acc1[a] = fmaf(s, W1, acc1[a]);
            } else if (mode == 1) {          // 4<=k<10: window wid
                acc1[a] = fmaf(s, W1, acc1[a]);
            } else {                          // k>=10: windows wid, wid+1
                acc1[a] = fmaf(s, W1, acc1[a]);
                acc2[a] = fmaf(s, W2, acc2[a]);
            }
        }
    };

    #pragma unroll
    for (int k = 0; k < 16; ++k) {
        const float W0 = (3.5f - (float)k) * (1.0f / 13.0f);                 // sy=wid-1 (k<=3)
        const float W1 = (13.0f - fabsf((float)k - 6.5f)) * (1.0f / 13.0f);  // sy=wid
        const float W2 = ((float)k - 9.5f) * (1.0f / 13.0f);                 // sy=wid+1 (k>=10)
        const int pr = r0 + k + 1;
        float gw = gauss[r0 + k] * GC;
        pixel(pr, vA, vC, gw, W0, W1, W2, (k <= 3) ? 0 : ((k < 10) ? 1 : 2));
        vA = vB; vB = vC;
        vC = patch[(pr + 2) * 65 + lane];    // row r+2 (pr+2 <= 66 for k<=15)
    }
    // ---- wave 3 extra: row 64 (sy=3 only, weight 3.5/13); vA=row63, vC=row65(pad) ----
    if (wid == 3) {
        pixel(66 - 1, vA, vC, gauss[64] * GC, 0.0f, 3.5f * (1.0f / 13.0f), 0.0f, 1);
    }

    // ---- flush accumulators (cross-wave merge; few atomics, negligible) ----
    {
        const int colbase = lane * PSTR;
        if (wid > 0) {
            #pragma unroll
            for (int a = 0; a < 8; ++a)
                atomicAdd(&part[colbase + (wid - 1) * 8 + a], acc0[a]);
        }
        #pragma unroll
        for (int a = 0; a < 8; ++a)
            atomicAdd(&part[colbase + wid * 8 + a], acc1[a]);
        if (wid < 3) {
            #pragma unroll
            for (int a = 0; a < 8; ++a)
                atomicAdd(&part[colbase + (wid + 1) * 8 + a], acc2[a]);
        }
    }

    // ---- column 64: lane k -> pixel row r0+k (padded-row LDS reads, no clamps) ----
    {
        const int nr = (wid == 3) ? 17 : 16;
        if (lane < nr) {
            int r  = r0 + lane;
            int pr = r + 1;
            float xu64 = patch[(pr - 1) * 65 + 64];
            float xc64 = patch[ pr      * 65 + 64];
            float xd64 = patch[(pr + 1) * 65 + 64];
            float xl63 = patch[ pr      * 65 + 63];
            float dx = xc64 - xl63;              // right neighbor replicates to xc64
            float dy = xd64 - xu64;
            float magw = sqrtf(fmaf(dx, dx, fmaf(dy, dy, 4e-10f))) * (gauss[r] * (0.5f * gauss[64]));
            float ang = fast_atan2f(dy, dx + 2e-10f);
            float o   = fmaf(ang, 1.27323954f, 8.0f);
            int bi = (int)o;
            float wo1 = o - (float)bi;
            int b0 = bi & 7;
            int b1 = (bi + 1) & 7;
            float q1 = wo1 * magw;
            float q0 = magw - q1;
            float* eb = &part[64 * PSTR];
            int syA = (r + 6) >> 4; if (syA > 3) syA = 3;
            float uA = (float)(r - 16 * syA + 6);
            float wA = (13.0f - fabsf(uA - 12.5f)) * (1.0f / 13.0f);
            atomicAdd(eb + syA * 8 + b0, q0 * wA);
            atomicAdd(eb + syA * 8 + b1, q1 * wA);
            int syB = syA - 1;
            if (syB >= 0) {
                float uB = (float)(r - 16 * syB + 6);
                float wB = (13.0f - fabsf(uB - 12.5f)) * (1.0f / 13.0f);
                if (wB > 0.0f) {
                    atomicAdd(eb + syB * 8 + b0, q0 * wB);
                    atomicAdd(eb + syB * 8 + b1, q1 * wB);
                }
            }
        }
    }
    __syncthreads();

    // ---- column pooling + double-normalize + store (wave 0) ----
    if (wid == 0) {
        float v[2];
        #pragma unroll
        for (int h = 0; h < 2; ++h) {
            int o  = lane + h * 64;
            int a  = o >> 4;
            int sy = (o >> 2) & 3;
            int sx = o & 3;
            float s = 0.0f;
            #pragma unroll 2
            for (int k = 0; k < 26; ++k) {
                int c = sx * 16 - 6 + k;
                if ((unsigned)c <= 64u) {
                    float wc = (13.0f - fabsf((float)k - 12.5f)) * (1.0f / 13.0f);
                    s = fmaf(wc, part[c * PSTR + sy * 8 + a], s);
                }
            }
            v[h] = s;
        }
        float ss = v[0] * v[0] + v[1] * v[1];
        #pragma unroll
        for (int off = 32; off > 0; off >>= 1) ss += __shfl_xor(ss, off, 64);
        float sc = 1.0f / fmaxf(sqrtf(ss), 1e-12f);
        v[0] = fminf(fmaxf(v[0] * sc, 0.0f), 0.2f);
        v[1] = fminf(fmaxf(v[1] * sc, 0.0f), 0.2f);
        ss = v[0] * v[0] + v[1] * v[1];
        #pragma unroll
        for (int off = 32; off > 0; off >>= 1) ss += __shfl_xor(ss, off, 64);
        sc = 1.0f / fmaxf(sqrtf(ss), 1e-12f);
        out[(size_t)m * 128 + lane]      = v[0] * sc;
        out[(size_t)m * 128 + lane + 64] = v[1] * sc;
    }
}

extern "C" void kernel_launch(void* const* d_in, const int* in_sizes, int n_in,
                              void* d_out, int out_size, void* d_ws, size_t ws_size,
                              hipStream_t stream) {
    const float* in = (const float*)d_in[0];
    float* out = (float*)d_out;
    sift_kernel<<<3072, 256, 0, stream>>>(in, out);
}

// Round 8
// 127.781 us; speedup vs baseline: 1.0094x; 1.0094x over previous
//
#include <hip/hip_runtime.h>
#include <math.h>

#define PSTR 33   // part[] col stride: 33 mod 32 = 1 -> lanes hit distinct banks

__device__ __forceinline__ float fast_atan2f(float y, float x) {
    float ax = fabsf(x), ay = fabsf(y);
    float mx = fmaxf(ax, ay);
    float mn = fminf(ax, ay);
    float a = mn * __builtin_amdgcn_rcpf(fmaxf(mx, 1e-30f));
    float s = a * a;
    float r = fmaf(s, fmaf(s, fmaf(s, fmaf(s, fmaf(s, -0.0117212f, 0.05265332f),
                    -0.11643287f), 0.19354346f), -0.33262347f), 0.99997726f) * a;
    r = (ay > ax) ? (1.57079637f - r) : r;
    r = (x < 0.0f) ? (3.14159274f - r) : r;
    return copysignf(r, y);
}

// Per-pixel front end: gradients from padded LDS rows, soft angle binning into
// named scalars s0..s7 (statically selected, no arrays anywhere).
#define PIXEL_FRONT(PR, GW)                                              \
    float xl = patch[(PR) * 65 + lm];                                    \
    float xr = patch[(PR) * 65 + lp];                                    \
    float dx = xr - xl;                                                  \
    float dy = vC - vA;                                                  \
    float magw = sqrtf(fmaf(dx, dx, fmaf(dy, dy, 4e-10f))) * (GW);       \
    float ang = fast_atan2f(dy, dx + 2e-10f);                            \
    float o = fmaf(ang, 1.27323954f, 8.0f);                              \
    int bi = (int)o;                                                     \
    float wo1 = o - (float)bi;                                           \
    int bn0 = bi & 7;                                                    \
    int bn1 = (bi + 1) & 7;                                              \
    float q1 = wo1 * magw;                                               \
    float q0 = magw - q1;                                                \
    float s0 = (bn0 == 0) ? q0 : ((bn1 == 0) ? q1 : 0.0f);               \
    float s1 = (bn0 == 1) ? q0 : ((bn1 == 1) ? q1 : 0.0f);               \
    float s2 = (bn0 == 2) ? q0 : ((bn1 == 2) ? q1 : 0.0f);               \
    float s3 = (bn0 == 3) ? q0 : ((bn1 == 3) ? q1 : 0.0f);               \
    float s4 = (bn0 == 4) ? q0 : ((bn1 == 4) ? q1 : 0.0f);               \
    float s5 = (bn0 == 5) ? q0 : ((bn1 == 5) ? q1 : 0.0f);               \
    float s6 = (bn0 == 6) ? q0 : ((bn1 == 6) ? q1 : 0.0f);               \
    float s7 = (bn0 == 7) ? q0 : ((bn1 == 7) ? q1 : 0.0f);

#define FMA8(P, W)                                                       \
    P##0 = fmaf(s0, (W), P##0); P##1 = fmaf(s1, (W), P##1);              \
    P##2 = fmaf(s2, (W), P##2); P##3 = fmaf(s3, (W), P##3);              \
    P##4 = fmaf(s4, (W), P##4); P##5 = fmaf(s5, (W), P##5);              \
    P##6 = fmaf(s6, (W), P##6); P##7 = fmaf(s7, (W), P##7);

#define FLUSH8(P, BASE)                                                  \
    atomicAdd(&part[(BASE) + 0], P##0); atomicAdd(&part[(BASE) + 1], P##1); \
    atomicAdd(&part[(BASE) + 2], P##2); atomicAdd(&part[(BASE) + 3], P##3); \
    atomicAdd(&part[(BASE) + 4], P##4); atomicAdd(&part[(BASE) + 5], P##5); \
    atomicAdd(&part[(BASE) + 6], P##6); atomicAdd(&part[(BASE) + 7], P##7);

// 4 waves/patch: wave w owns rows [16w,16w+16) (+row 64 for wave 3). lane = column.
// Row-padded LDS patch ([67][65]); 24 NAMED scalar accumulators (no spillable
// aggregates); launch_bounds(256,4) = R3's proven no-spill allocator regime.
__global__ __launch_bounds__(256, 4)
void sift_kernel(const float* __restrict__ in, float* __restrict__ out) {
    __shared__ float patch[67 * 65];   // padded row pr = r+1 (r in [-1,65])
    __shared__ float part[65 * PSTR];  // [column][sy*8 + a]
    __shared__ float gauss[65];

    const int tid  = threadIdx.x;
    const int lane = tid & 63;
    const int wid  = tid >> 6;
    const int m    = blockIdx.x;
    const int bc   = m >> 6;
    const int ij   = m & 63;
    const float* src = in + (size_t)bc * (520 * 520) + (ij >> 3) * (65 * 520) + (ij & 7) * 65;

    // ---- stage row-padded patch to LDS (rows clamped -> replicate pad) ----
    for (int k = tid; k < 67 * 65; k += 256) {
        int y = k / 65;
        int x = k - y * 65;
        int sy = y - 1; sy = (sy < 0) ? 0 : ((sy > 64) ? 64 : sy);
        patch[k] = src[sy * 520 + x];
    }
    // ---- zero partials ----
    for (int k = tid; k < 65 * PSTR; k += 256) part[k] = 0.0f;
    // ---- gaussian (wave 0): sigma = 65/sqrt(2) -> 2*sigma^2 = 4225 ----
    if (wid == 0) {
        float dd = (float)(lane - 32);
        float e  = __expf(-(dd * dd) * (1.0f / 4225.0f));
        float ssum = e;
        #pragma unroll
        for (int off = 32; off > 0; off >>= 1) ssum += __shfl_xor(ssum, off, 64);
        const float e64 = __expf(-1024.0f / 4225.0f);
        float inv = 1.0f / (ssum + e64);
        gauss[lane] = e * inv;
        if (lane == 0) gauss[64] = e64 * inv;
    }
    __syncthreads();

    const float GC = 0.5f * gauss[lane];   // column gaussian (0.5 grad scale folded)
    const int r0 = wid * 16;
    const int lm = (lane > 0) ? lane - 1 : 0;   // left col (replicate at 0)
    const int lp = lane + 1;                    // right col (col 64 is real data)

    // named accumulators: A = window wid-1, B = window wid, C = window wid+1
    float A0=0,A1=0,A2=0,A3=0,A4=0,A5=0,A6=0,A7=0;
    float B0=0,B1=0,B2=0,B3=0,B4=0,B5=0,B6=0,B7=0;
    float C0=0,C1=0,C2=0,C3=0,C4=0,C5=0,C6=0,C7=0;

    // rolling rows (padded indices): vA=pr-1, vB=pr, vC=pr+1
    float vA = patch[(r0    ) * 65 + lane];
    float vB = patch[(r0 + 1) * 65 + lane];
    float vC = patch[(r0 + 2) * 65 + lane];

    #pragma unroll
    for (int k = 0; k <= 3; ++k) {               // windows wid-1, wid
        const int pr = r0 + k + 1;
        const float W0 = (3.5f - (float)k) * (1.0f / 13.0f);
        const float W1 = (13.0f - fabsf((float)k - 6.5f)) * (1.0f / 13.0f);
        const float gw = gauss[r0 + k] * GC;
        PIXEL_FRONT(pr, gw)
        FMA8(A, W0)
        FMA8(B, W1)
        vA = vB; vB = vC; vC = patch[(pr + 2) * 65 + lane];
    }
    #pragma unroll
    for (int k = 4; k <= 9; ++k) {               // window wid only
        const int pr = r0 + k + 1;
        const float W1 = (13.0f - fabsf((float)k - 6.5f)) * (1.0f / 13.0f);
        const float gw = gauss[r0 + k] * GC;
        PIXEL_FRONT(pr, gw)
        FMA8(B, W1)
        vA = vB; vB = vC; vC = patch[(pr + 2) * 65 + lane];
    }
    #pragma unroll
    for (int k = 10; k <= 15; ++k) {             // windows wid, wid+1
        const int pr = r0 + k + 1;
        const float W1 = (13.0f - fabsf((float)k - 6.5f)) * (1.0f / 13.0f);
        const float W2 = ((float)k - 9.5f) * (1.0f / 13.0f);
        const float gw = gauss[r0 + k] * GC;
        PIXEL_FRONT(pr, gw)
        FMA8(B, W1)
        FMA8(C, W2)
        vA = vB; vB = vC; vC = patch[(pr + 2) * 65 + lane];
    }
    // wave 3 extra: row 64 (window sy=3 only, weight 3.5/13); vA=row63, vC=row65(pad)
    if (wid == 3) {
        const float W1 = 3.5f * (1.0f / 13.0f);
        const float gw = gauss[64] * GC;
        PIXEL_FRONT(65, gw)
        FMA8(B, W1)
    }

    // ---- flush accumulators (cross-wave merge; 24 atomics/lane, negligible) ----
    {
        const int colbase = lane * PSTR;
        if (wid > 0) { FLUSH8(A, colbase + (wid - 1) * 8) }
        FLUSH8(B, colbase + wid * 8)
        if (wid < 3) { FLUSH8(C, colbase + (wid + 1) * 8) }
    }

    // ---- column 64: lane k -> pixel row r0+k (padded-row LDS reads) ----
    {
        const int nr = (wid == 3) ? 17 : 16;
        if (lane < nr) {
            int r  = r0 + lane;
            int pr = r + 1;
            float xu64 = patch[(pr - 1) * 65 + 64];
            float xc64 = patch[ pr      * 65 + 64];
            float xd64 = patch[(pr + 1) * 65 + 64];
            float xl63 = patch[ pr      * 65 + 63];
            float dx = xc64 - xl63;              // right neighbor replicates to xc64
            float dy = xd64 - xu64;
            float magw = sqrtf(fmaf(dx, dx, fmaf(dy, dy, 4e-10f))) * (gauss[r] * (0.5f * gauss[64]));
            float ang = fast_atan2f(dy, dx + 2e-10f);
            float o   = fmaf(ang, 1.27323954f, 8.0f);
            int bi = (int)o;
            float wo1 = o - (float)bi;
            int b0 = bi & 7;
            int b1 = (bi + 1) & 7;
            float q1 = wo1 * magw;
            float q0 = magw - q1;
            float* eb = &part[64 * PSTR];
            int syA = (r + 6) >> 4; if (syA > 3) syA = 3;
            float uA = (float)(r - 16 * syA + 6);
            float wA = (13.0f - fabsf(uA - 12.5f)) * (1.0f / 13.0f);
            atomicAdd(eb + syA * 8 + b0, q0 * wA);
            atomicAdd(eb + syA * 8 + b1, q1 * wA);
            int syB = syA - 1;
            if (syB >= 0) {
                float uB = (float)(r - 16 * syB + 6);
                float wB = (13.0f - fabsf(uB - 12.5f)) * (1.0f / 13.0f);
                if (wB > 0.0f) {
                    atomicAdd(eb + syB * 8 + b0, q0 * wB);
                    atomicAdd(eb + syB * 8 + b1, q1 * wB);
                }
            }
        }
    }
    __syncthreads();

    // ---- column pooling + double-normalize + store (wave 0) ----
    if (wid == 0) {
        float v0, v1;
        #pragma unroll
        for (int h = 0; h < 2; ++h) {
            int o  = lane + h * 64;
            int a  = o >> 4;
            int sy = (o >> 2) & 3;
            int sx = o & 3;
            float s = 0.0f;
            #pragma unroll 2
            for (int k = 0; k < 26; ++k) {
                int c = sx * 16 - 6 + k;
                if ((unsigned)c <= 64u) {
                    float wc = (13.0f - fabsf((float)k - 12.5f)) * (1.0f / 13.0f);
                    s = fmaf(wc, part[c * PSTR + sy * 8 + a], s);
                }
            }
            if (h == 0) v0 = s; else v1 = s;
        }
        float ss = v0 * v0 + v1 * v1;
        #pragma unroll
        for (int off = 32; off > 0; off >>= 1) ss += __shfl_xor(ss, off, 64);
        float sc = 1.0f / fmaxf(sqrtf(ss), 1e-12f);
        v0 = fminf(fmaxf(v0 * sc, 0.0f), 0.2f);
        v1 = fminf(fmaxf(v1 * sc, 0.0f), 0.2f);
        ss = v0 * v0 + v1 * v1;
        #pragma unroll
        for (int off = 32; off > 0; off >>= 1) ss += __shfl_xor(ss, off, 64);
        sc = 1.0f / fmaxf(sqrtf(ss), 1e-12f);
        out[(size_t)m * 128 + lane]      = v0 * sc;
        out[(size_t)m * 128 + lane + 64] = v1 * sc;
    }
}

extern "C" void kernel_launch(void* const* d_in, const int* in_sizes, int n_in,
                              void* d_out, int out_size, void* d_ws, size_t ws_size,
                              hipStream_t stream) {
    const float* in = (const float*)d_in[0];
    float* out = (float*)d_out;
    sift_kernel<<<3072, 256, 0, stream>>>(in, out);
}

// Round 9
// 79.787 us; speedup vs baseline: 1.6165x; 1.6015x over previous
//
#include <hip/hip_runtime.h>
#include <math.h>

#define PSTR 33   // part[] col stride: 33 mod 32 = 1 -> 2-way bank aliasing (free)

__device__ __forceinline__ float fast_atan2f(float y, float x) {
    float ax = fabsf(x), ay = fabsf(y);
    float mx = fmaxf(ax, ay);
    float mn = fminf(ax, ay);
    float a = mn * __builtin_amdgcn_rcpf(fmaxf(mx, 1e-30f));
    float s = a * a;
    float r = fmaf(s, fmaf(s, fmaf(s, fmaf(s, fmaf(s, -0.0117212f, 0.05265332f),
                    -0.11643287f), 0.19354346f), -0.33262347f), 0.99997726f) * a;
    r = (ay > ax) ? (1.57079637f - r) : r;
    r = (x < 0.0f) ? (3.14159274f - r) : r;
    return copysignf(r, y);
}

// triangular row-pool weight for window SY at row RR (compile-time folded)
#define WGT(SY, RR) ((13.0f - fabsf((float)(RR) - 16.0f * (SY) - 6.5f)) * (1.0f / 13.0f))

#define FMA8(P, W)                                                        \
    P##0 = fmaf(s0, (W), P##0); P##1 = fmaf(s1, (W), P##1);               \
    P##2 = fmaf(s2, (W), P##2); P##3 = fmaf(s3, (W), P##3);               \
    P##4 = fmaf(s4, (W), P##4); P##5 = fmaf(s5, (W), P##5);               \
    P##6 = fmaf(s6, (W), P##6); P##7 = fmaf(s7, (W), P##7);

// One pixel at (row RR, col lane). Rows live in register array R; RRI is the
// index of row RR in R. dy from registers; dx via wave shuffles; no LDS reads
// except the uniform col-64 broadcast.
#define PIX(R, RRI, RR, ACCUM)                                            \
    {                                                                     \
        const int r_ = (RR);                                              \
        float grow = (r_ < 64) ? __shfl(G, r_, 64) : g64;                 \
        float gw = grow * GC;                                             \
        float c64r = c64buf[r_ + 1];                                      \
        float xc = R[RRI];                                                \
        float xl = __shfl_up(xc, 1, 64);   if (lane == 0)  xl = xc;       \
        float xr = __shfl_down(xc, 1, 64); if (lane == 63) xr = c64r;     \
        float dx = xr - xl;                                               \
        float dy = R[(RRI) + 1] - R[(RRI) - 1];                           \
        float magw = sqrtf(fmaf(dx, dx, fmaf(dy, dy, 4e-10f))) * gw;      \
        float ang = fast_atan2f(dy, dx + 2e-10f);                         \
        float o = fmaf(ang, 1.27323954f, 8.0f);                           \
        int bi = (int)o;                                                  \
        float wo1 = o - (float)bi;                                        \
        int bn0 = bi & 7;                                                 \
        int bn1 = (bi + 1) & 7;                                           \
        float q1 = wo1 * magw;                                            \
        float q0 = magw - q1;                                             \
        float s0 = (bn0 == 0) ? q0 : ((bn1 == 0) ? q1 : 0.0f);            \
        float s1 = (bn0 == 1) ? q0 : ((bn1 == 1) ? q1 : 0.0f);            \
        float s2 = (bn0 == 2) ? q0 : ((bn1 == 2) ? q1 : 0.0f);            \
        float s3 = (bn0 == 3) ? q0 : ((bn1 == 3) ? q1 : 0.0f);            \
        float s4 = (bn0 == 4) ? q0 : ((bn1 == 4) ? q1 : 0.0f);            \
        float s5 = (bn0 == 5) ? q0 : ((bn1 == 5) ? q1 : 0.0f);            \
        float s6 = (bn0 == 6) ? q0 : ((bn1 == 6) ? q1 : 0.0f);            \
        float s7 = (bn0 == 7) ? q0 : ((bn1 == 7) ? q1 : 0.0f);            \
        ACCUM                                                             \
    }

// One wave per patch, lane = column. Patch columns live in REGISTERS, loaded
// in two fully-unrolled batches (one latency exposure each, pinned by asm
// keep-alives). No barriers, no cross-wave merge; lane-private part[] columns.
__global__ __launch_bounds__(64, 4)
void sift_kernel(const float* __restrict__ in, float* __restrict__ out) {
    __shared__ float part[65 * PSTR];  // [column][sy*8 + a]
    __shared__ float c64buf[67];       // col-64 rows -1..65 (clamped)

    const int lane = threadIdx.x;
    const int m  = blockIdx.x;
    const int bc = m >> 6;
    const int ij = m & 63;
    const float* src = in + (size_t)bc * (520 * 520) + (ij >> 3) * (65 * 520) + (ij & 7) * 65;

    // ---- staging: col-64 halo, col-63 (per-row left neighbor), zero col-64 slots ----
    {
        int rr = lane - 1; rr = (rr < 0) ? 0 : rr;
        c64buf[lane] = src[rr * 520 + 64];
        if (lane < 3) {
            int r2 = 63 + lane; r2 = (r2 > 64) ? 64 : r2;
            c64buf[64 + lane] = src[r2 * 520 + 64];
        }
        if (lane < 32) part[64 * PSTR + lane] = 0.0f;
    }
    float xl63  = src[lane * 520 + 63];   // col63[row=lane], rows 0..63
    float xl63b = src[64 * 520 + 63];     // col63[row=64] (uniform broadcast load)

    // ---- gaussian in registers: G holds gauss(lane); g64 = gauss(64) ----
    float dd = (float)(lane - 32);
    float E  = __expf(-(dd * dd) * (1.0f / 4225.0f));
    float ssum = E;
    #pragma unroll
    for (int off = 32; off > 0; off >>= 1) ssum += __shfl_xor(ssum, off, 64);
    const float e64 = __expf(-1024.0f / 4225.0f);
    float inv = 1.0f / (ssum + e64);
    float G   = E * inv;
    float g64 = e64 * inv;
    const float GC = 0.5f * G;     // own-column gaussian with 0.5 grad scale folded

    const int cb = lane * PSTR;

    // w2 partial carried across phases in registers
    float C0=0,C1=0,C2=0,C3=0,C4=0,C5=0,C6=0,C7=0;

    // ================= PHASE 1: rows 0..35 (windows 0,1,2-partial) =================
    {
        float R[38];   // R[i] = row (i-1), clamped (row -1 -> row 0)
        #pragma unroll
        for (int i = 0; i < 38; ++i) {
            int rr = i - 1; rr = (rr < 0) ? 0 : rr;
            R[i] = src[rr * 520 + lane];
        }
        #pragma unroll
        for (int i = 0; i < 38; ++i) asm volatile("" : "+v"(R[i]));  // pin: no load sinking

        float A0=0,A1=0,A2=0,A3=0,A4=0,A5=0,A6=0,A7=0;   // window 0
        float B0=0,B1=0,B2=0,B3=0,B4=0,B5=0,B6=0,B7=0;   // window 1

        #pragma unroll
        for (int r = 0; r < 10; ++r)   PIX(R, r + 1, r, FMA8(A, WGT(0, r)))
        #pragma unroll
        for (int r = 10; r < 20; ++r)  PIX(R, r + 1, r, FMA8(A, WGT(0, r)) FMA8(B, WGT(1, r)))
        #pragma unroll
        for (int r = 20; r < 26; ++r)  PIX(R, r + 1, r, FMA8(B, WGT(1, r)))
        #pragma unroll
        for (int r = 26; r < 36; ++r)  PIX(R, r + 1, r, FMA8(B, WGT(1, r)) FMA8(C, WGT(2, r)))

        part[cb + 0] = A0; part[cb + 1] = A1; part[cb + 2] = A2; part[cb + 3] = A3;
        part[cb + 4] = A4; part[cb + 5] = A5; part[cb + 6] = A6; part[cb + 7] = A7;
        part[cb + 8] = B0; part[cb + 9] = B1; part[cb +10] = B2; part[cb +11] = B3;
        part[cb +12] = B4; part[cb +13] = B5; part[cb +14] = B6; part[cb +15] = B7;
    }

    // ================= PHASE 2: rows 36..64 (windows 2-rest, 3) =================
    {
        float R[31];   // R[i] = row (35+i), clamped (row 65 -> row 64)
        #pragma unroll
        for (int i = 0; i < 31; ++i) {
            int rr = 35 + i; rr = (rr > 64) ? 64 : rr;
            R[i] = src[rr * 520 + lane];
        }
        #pragma unroll
        for (int i = 0; i < 31; ++i) asm volatile("" : "+v"(R[i]));  // pin

        float D0=0,D1=0,D2=0,D3=0,D4=0,D5=0,D6=0,D7=0;   // window 2 (rows 36..51)
        float F0=0,F1=0,F2=0,F3=0,F4=0,F5=0,F6=0,F7=0;   // window 3

        #pragma unroll
        for (int r = 36; r < 42; ++r)  PIX(R, r - 35, r, FMA8(D, WGT(2, r)))
        #pragma unroll
        for (int r = 42; r < 52; ++r)  PIX(R, r - 35, r, FMA8(D, WGT(2, r)) FMA8(F, WGT(3, r)))
        #pragma unroll
        for (int r = 52; r < 65; ++r)  PIX(R, r - 35, r, FMA8(F, WGT(3, r)))

        part[cb +16] = C0 + D0; part[cb +17] = C1 + D1; part[cb +18] = C2 + D2;
        part[cb +19] = C3 + D3; part[cb +20] = C4 + D4; part[cb +21] = C5 + D5;
        part[cb +22] = C6 + D6; part[cb +23] = C7 + D7;
        part[cb +24] = F0; part[cb +25] = F1; part[cb +26] = F2; part[cb +27] = F3;
        part[cb +28] = F4; part[cb +29] = F5; part[cb +30] = F6; part[cb +31] = F7;
    }

    // ================= column 64: rows 0..63 (lane=row) + row 64 (lane 0) =========
    {
        int r = lane;
        float xu  = c64buf[r];         // col64[r-1]
        float xcc = c64buf[r + 1];     // col64[r]
        float xd  = c64buf[r + 2];     // col64[r+1]
        float dx = xcc - xl63;         // right neighbor replicates to xcc
        float dy = xd - xu;
        float magw = sqrtf(fmaf(dx, dx, fmaf(dy, dy, 4e-10f))) * (G * (0.5f * g64));
        float ang = fast_atan2f(dy, dx + 2e-10f);
        float o   = fmaf(ang, 1.27323954f, 8.0f);
        int bi = (int)o;
        float wo1 = o - (float)bi;
        int b0 = bi & 7;
        int b1 = (bi + 1) & 7;
        float q1 = wo1 * magw;
        float q0 = magw - q1;
        float* eb = &part[64 * PSTR];
        int syA = (r + 6) >> 4; if (syA > 3) syA = 3;
        float uA = (float)(r - 16 * syA + 6);
        float wA = (13.0f - fabsf(uA - 12.5f)) * (1.0f / 13.0f);
        atomicAdd(eb + syA * 8 + b0, q0 * wA);
        atomicAdd(eb + syA * 8 + b1, q1 * wA);
        int syB = syA - 1;
        if (syB >= 0) {
            float uB = (float)(r - 16 * syB + 6);
            float wB = (13.0f - fabsf(uB - 12.5f)) * (1.0f / 13.0f);
            if (wB > 0.0f) {
                atomicAdd(eb + syB * 8 + b0, q0 * wB);
                atomicAdd(eb + syB * 8 + b1, q1 * wB);
            }
        }
        if (lane == 0) {   // row 64 of column 64 (window 3 only)
            float xu2  = c64buf[64];   // row 63
            float xc2  = c64buf[65];   // row 64
            float xd2  = c64buf[66];   // row 65 -> 64 (replicate)
            float dx2 = xc2 - xl63b;
            float dy2 = xd2 - xu2;
            float mg = sqrtf(fmaf(dx2, dx2, fmaf(dy2, dy2, 4e-10f))) * (g64 * (0.5f * g64));
            float an = fast_atan2f(dy2, dx2 + 2e-10f);
            float o2 = fmaf(an, 1.27323954f, 8.0f);
            int bi2 = (int)o2;
            float w1 = o2 - (float)bi2;
            int c0 = bi2 & 7;
            int c1 = (bi2 + 1) & 7;
            float p1 = w1 * mg;
            float p0 = mg - p1;
            const float w64 = 3.5f * (1.0f / 13.0f);   // row 64, window 3
            atomicAdd(eb + 3 * 8 + c0, p0 * w64);
            atomicAdd(eb + 3 * 8 + c1, p1 * w64);
        }
    }

    // ================= column pooling + double-normalize + store ==================
    {
        float v0, v1;
        #pragma unroll
        for (int h = 0; h < 2; ++h) {
            int o  = lane + h * 64;
            int a  = o >> 4;
            int sy = (o >> 2) & 3;
            int sx = o & 3;
            float s = 0.0f;
            #pragma unroll 2
            for (int k = 0; k < 26; ++k) {
                int c = sx * 16 - 6 + k;
                if ((unsigned)c <= 64u) {
                    float wc = (13.0f - fabsf((float)k - 12.5f)) * (1.0f / 13.0f);
                    s = fmaf(wc, part[c * PSTR + sy * 8 + a], s);
                }
            }
            if (h == 0) v0 = s; else v1 = s;
        }
        float ss = v0 * v0 + v1 * v1;
        #pragma unroll
        for (int off = 32; off > 0; off >>= 1) ss += __shfl_xor(ss, off, 64);
        float sc = 1.0f / fmaxf(sqrtf(ss), 1e-12f);
        v0 = fminf(fmaxf(v0 * sc, 0.0f), 0.2f);
        v1 = fminf(fmaxf(v1 * sc, 0.0f), 0.2f);
        ss = v0 * v0 + v1 * v1;
        #pragma unroll
        for (int off = 32; off > 0; off >>= 1) ss += __shfl_xor(ss, off, 64);
        sc = 1.0f / fmaxf(sqrtf(ss), 1e-12f);
        out[(size_t)m * 128 + lane]      = v0 * sc;
        out[(size_t)m * 128 + lane + 64] = v1 * sc;
    }
}

extern "C" void kernel_launch(void* const* d_in, const int* in_sizes, int n_in,
                              void* d_out, int out_size, void* d_ws, size_t ws_size,
                              hipStream_t stream) {
    const float* in = (const float*)d_in[0];
    float* out = (float*)d_out;
    sift_kernel<<<3072, 64, 0, stream>>>(in, out);
}

// Round 10
// 49.495 us; speedup vs baseline: 2.6059x; 1.6120x over previous
//
#include <hip/hip_runtime.h>
#include <math.h>

#define PSTR 33   // part[] col stride: 33 mod 32 = 1 -> benign 2-way bank aliasing

__device__ __forceinline__ float fast_atan2f(float y, float x) {
    float ax = fabsf(x), ay = fabsf(y);
    float mx = fmaxf(ax, ay);
    float mn = fminf(ax, ay);
    float a = mn * __builtin_amdgcn_rcpf(fmaxf(mx, 1e-30f));
    float s = a * a;
    float r = fmaf(s, fmaf(s, fmaf(s, fmaf(s, fmaf(s, -0.0117212f, 0.05265332f),
                    -0.11643287f), 0.19354346f), -0.33262347f), 0.99997726f) * a;
    r = (ay > ax) ? (1.57079637f - r) : r;
    r = (x < 0.0f) ? (3.14159274f - r) : r;
    return copysignf(r, y);
}

// triangular row-pool weight for window SY at row RR (compile-time literal)
#define WGT(SY, RR) ((13.0f - fabsf((float)(RR) - 16.0f * (SY) - 6.5f)) * (1.0f / 13.0f))

#define FMA8(P, W)                                                        \
    P##0 = fmaf(s0, (W), P##0); P##1 = fmaf(s1, (W), P##1);               \
    P##2 = fmaf(s2, (W), P##2); P##3 = fmaf(s3, (W), P##3);               \
    P##4 = fmaf(s4, (W), P##4); P##5 = fmaf(s5, (W), P##5);               \
    P##6 = fmaf(s6, (W), P##6); P##7 = fmaf(s7, (W), P##7);

// gauss(row) from per-lane register G via readlane with compile-time lane
#define RDL(RR) __uint_as_float((unsigned)__builtin_amdgcn_readlane((int)__float_as_uint(G), (RR)))

// One pixel at (row RR, col lane). Row data in register array ARR (xc=ARR[I]).
// dy register-register; dx via 2 shuffles; gauss(row) via readlane. No LDS.
#define PIX(ARR, I, RR, ACCUM)                                            \
    {                                                                     \
        float grow = ((RR) < 64) ? RDL((RR) & 63) : g64;                  \
        float gw = grow * GC;                                             \
        float c64r = c64buf[(RR) + 1];                                    \
        float xc = ARR[I];                                                \
        float xl = __shfl_up(xc, 1, 64);   if (lane == 0)  xl = xc;       \
        float xr = __shfl_down(xc, 1, 64); if (lane == 63) xr = c64r;     \
        float dx = xr - xl;                                               \
        float dy = ARR[(I) + 1] - ARR[(I) - 1];                           \
        float magw = sqrtf(fmaf(dx, dx, fmaf(dy, dy, 4e-10f))) * gw;      \
        float ang = fast_atan2f(dy, dx + 2e-10f);                         \
        float o = fmaf(ang, 1.27323954f, 8.0f);                           \
        int bi = (int)o;                                                  \
        float wo1 = o - (float)bi;                                        \
        int bn0 = bi & 7;                                                 \
        int bn1 = (bi + 1) & 7;                                           \
        float q1 = wo1 * magw;                                            \
        float q0 = magw - q1;                                             \
        float s0 = (bn0 == 0) ? q0 : ((bn1 == 0) ? q1 : 0.0f);            \
        float s1 = (bn0 == 1) ? q0 : ((bn1 == 1) ? q1 : 0.0f);            \
        float s2 = (bn0 == 2) ? q0 : ((bn1 == 2) ? q1 : 0.0f);            \
        float s3 = (bn0 == 3) ? q0 : ((bn1 == 3) ? q1 : 0.0f);            \
        float s4 = (bn0 == 4) ? q0 : ((bn1 == 4) ? q1 : 0.0f);            \
        float s5 = (bn0 == 5) ? q0 : ((bn1 == 5) ? q1 : 0.0f);            \
        float s6 = (bn0 == 6) ? q0 : ((bn1 == 6) ? q1 : 0.0f);            \
        float s7 = (bn0 == 7) ? q0 : ((bn1 == 7) ? q1 : 0.0f);            \
        ACCUM                                                             \
    }

#define LOAD_RA(BASE)                                                     \
    _Pragma("unroll")                                                     \
    for (int i = 0; i < 18; ++i) {                                        \
        int rr = (BASE) + i; rr = (rr < 0) ? 0 : ((rr > 64) ? 64 : rr);   \
        RA[i] = src[rr * 520 + lane];                                     \
    }
#define LOAD_RB(BASE)                                                     \
    _Pragma("unroll")                                                     \
    for (int i = 0; i < 19; ++i) {                                        \
        int rr = (BASE) + i; rr = (rr < 0) ? 0 : ((rr > 64) ? 64 : rr);   \
        RB[i] = src[rr * 520 + lane];                                     \
    }
#define PIN_RA  _Pragma("unroll") for (int i = 0; i < 18; ++i) asm volatile("" : "+v"(RA[i]));
#define PIN_RB  _Pragma("unroll") for (int i = 0; i < 19; ++i) asm volatile("" : "+v"(RB[i]));

// One wave per patch, lane = column. Rows live in two alternating register
// buffers, double-buffered across 4 phases (loads for phase k+1 in flight
// while phase k computes). waves_per_eu max=3 -> ~170-VGPR budget, no spill.
__global__ __launch_bounds__(64)
__attribute__((amdgpu_waves_per_eu(2, 3)))
void sift_kernel(const float* __restrict__ in, float* __restrict__ out) {
    __shared__ float part[65 * PSTR];  // [column][sy*8 + a]
    __shared__ float c64buf[67];       // col-64 rows -1..65 (clamped)

    const int lane = threadIdx.x;
    const int m  = blockIdx.x;
    const int bc = m >> 6;
    const int ij = m & 63;
    const float* src = in + (size_t)bc * (520 * 520) + (ij >> 3) * (65 * 520) + (ij & 7) * 65;

    // ---- staging: col-64 halo, col-63 neighbors, zero col-64 part slots ----
    {
        int rr = lane - 1; rr = (rr < 0) ? 0 : rr;
        c64buf[lane] = src[rr * 520 + 64];
        if (lane < 3) {
            int r2 = 63 + lane; r2 = (r2 > 64) ? 64 : r2;
            c64buf[64 + lane] = src[r2 * 520 + 64];
        }
        if (lane < 32) part[64 * PSTR + lane] = 0.0f;
    }
    float xl63  = src[lane * 520 + 63];   // col63[row=lane]
    float xl63b = src[64 * 520 + 63];     // col63[row=64] (broadcast)

    // ---- row-buffer loads: phase A (rows -1..16) and phase B (rows 15..33) ----
    float RA[18], RB[19];
    LOAD_RA(-1)
    LOAD_RB(15)

    // ---- gaussian: G = gauss(lane), g64 = gauss(64); sigma=65/sqrt(2) ----
    float dd = (float)(lane - 32);
    float E  = __expf(-(dd * dd) * (1.0f / 4225.0f));
    float ssum = E;
    #pragma unroll
    for (int off = 32; off > 0; off >>= 1) ssum += __shfl_xor(ssum, off, 64);
    const float e64 = __expf(-1024.0f / 4225.0f);
    float inv = 1.0f / (ssum + e64);
    float G   = E * inv;
    float g64 = e64 * inv;
    const float GC = 0.5f * G;     // own-column gaussian, 0.5 grad scale folded

    const int cb = lane * PSTR;

    float A0=0,A1=0,A2=0,A3=0,A4=0,A5=0,A6=0,A7=0;   // window 0
    float B0=0,B1=0,B2=0,B3=0,B4=0,B5=0,B6=0,B7=0;   // window 1
    float C0=0,C1=0,C2=0,C3=0,C4=0,C5=0,C6=0,C7=0;   // window 2
    float F0=0,F1=0,F2=0,F3=0,F4=0,F5=0,F6=0,F7=0;   // window 3

    // ======= PHASE A: rows 0..15 (RA[i]=row i-1) =======
    PIN_RA
    #pragma unroll
    for (int r = 0; r < 10; ++r)   PIX(RA, r + 1, r, FMA8(A, WGT(0, r)))
    #pragma unroll
    for (int r = 10; r < 16; ++r)  PIX(RA, r + 1, r, FMA8(A, WGT(0, r)) FMA8(B, WGT(1, r)))

    // refill RA with phase-C rows (31..48); drain RB for phase B
    LOAD_RA(31)
    PIN_RB
    // ======= PHASE B: rows 16..31 (RB[i]=row 15+i) =======
    #pragma unroll
    for (int r = 16; r < 20; ++r)  PIX(RB, r - 15, r, FMA8(A, WGT(0, r)) FMA8(B, WGT(1, r)))
    #pragma unroll
    for (int r = 20; r < 26; ++r)  PIX(RB, r - 15, r, FMA8(B, WGT(1, r)))
    #pragma unroll
    for (int r = 26; r < 32; ++r)  PIX(RB, r - 15, r, FMA8(B, WGT(1, r)) FMA8(C, WGT(2, r)))
    // flush window 0
    part[cb + 0] = A0; part[cb + 1] = A1; part[cb + 2] = A2; part[cb + 3] = A3;
    part[cb + 4] = A4; part[cb + 5] = A5; part[cb + 6] = A6; part[cb + 7] = A7;

    // refill RB with phase-D rows (47..65); drain RA for phase C
    LOAD_RB(47)
    PIN_RA
    // ======= PHASE C: rows 32..47 (RA[i]=row 31+i) =======
    #pragma unroll
    for (int r = 32; r < 36; ++r)  PIX(RA, r - 31, r, FMA8(B, WGT(1, r)) FMA8(C, WGT(2, r)))
    #pragma unroll
    for (int r = 36; r < 42; ++r)  PIX(RA, r - 31, r, FMA8(C, WGT(2, r)))
    #pragma unroll
    for (int r = 42; r < 48; ++r)  PIX(RA, r - 31, r, FMA8(C, WGT(2, r)) FMA8(F, WGT(3, r)))
    // flush window 1
    part[cb + 8] = B0; part[cb + 9] = B1; part[cb +10] = B2; part[cb +11] = B3;
    part[cb +12] = B4; part[cb +13] = B5; part[cb +14] = B6; part[cb +15] = B7;

    PIN_RB
    // ======= PHASE D: rows 48..64 (RB[i]=row 47+i) =======
    #pragma unroll
    for (int r = 48; r < 52; ++r)  PIX(RB, r - 47, r, FMA8(C, WGT(2, r)) FMA8(F, WGT(3, r)))
    #pragma unroll
    for (int r = 52; r < 65; ++r)  PIX(RB, r - 47, r, FMA8(F, WGT(3, r)))
    // flush windows 2 and 3
    part[cb +16] = C0; part[cb +17] = C1; part[cb +18] = C2; part[cb +19] = C3;
    part[cb +20] = C4; part[cb +21] = C5; part[cb +22] = C6; part[cb +23] = C7;
    part[cb +24] = F0; part[cb +25] = F1; part[cb +26] = F2; part[cb +27] = F3;
    part[cb +28] = F4; part[cb +29] = F5; part[cb +30] = F6; part[cb +31] = F7;

    // ======= column 64: rows 0..63 (lane=row) + row 64 (lane 0) =======
    {
        int r = lane;
        float xu  = c64buf[r];         // col64[r-1]
        float xcc = c64buf[r + 1];     // col64[r]
        float xd  = c64buf[r + 2];     // col64[r+1]
        float dx = xcc - xl63;         // right neighbor replicates to xcc
        float dy = xd - xu;
        float magw = sqrtf(fmaf(dx, dx, fmaf(dy, dy, 4e-10f))) * (G * (0.5f * g64));
        float ang = fast_atan2f(dy, dx + 2e-10f);
        float o   = fmaf(ang, 1.27323954f, 8.0f);
        int bi = (int)o;
        float wo1 = o - (float)bi;
        int b0 = bi & 7;
        int b1 = (bi + 1) & 7;
        float q1 = wo1 * magw;
        float q0 = magw - q1;
        float* eb = &part[64 * PSTR];
        int syA = (r + 6) >> 4; if (syA > 3) syA = 3;
        float uA = (float)(r - 16 * syA + 6);
        float wA = (13.0f - fabsf(uA - 12.5f)) * (1.0f / 13.0f);
        atomicAdd(eb + syA * 8 + b0, q0 * wA);
        atomicAdd(eb + syA * 8 + b1, q1 * wA);
        int syB = syA - 1;
        if (syB >= 0) {
            float uB = (float)(r - 16 * syB + 6);
            float wB = (13.0f - fabsf(uB - 12.5f)) * (1.0f / 13.0f);
            if (wB > 0.0f) {
                atomicAdd(eb + syB * 8 + b0, q0 * wB);
                atomicAdd(eb + syB * 8 + b1, q1 * wB);
            }
        }
        if (lane == 0) {   // pixel (64,64): window 3 only
            float xu2  = c64buf[64];
            float xc2  = c64buf[65];
            float xd2  = c64buf[66];
            float dx2 = xc2 - xl63b;
            float dy2 = xd2 - xu2;
            float mg = sqrtf(fmaf(dx2, dx2, fmaf(dy2, dy2, 4e-10f))) * (g64 * (0.5f * g64));
            float an = fast_atan2f(dy2, dx2 + 2e-10f);
            float o2 = fmaf(an, 1.27323954f, 8.0f);
            int bi2 = (int)o2;
            float w1 = o2 - (float)bi2;
            int c0 = bi2 & 7;
            int c1 = (bi2 + 1) & 7;
            float p1 = w1 * mg;
            float p0 = mg - p1;
            const float w64 = 3.5f * (1.0f / 13.0f);
            atomicAdd(eb + 3 * 8 + c0, p0 * w64);
            atomicAdd(eb + 3 * 8 + c1, p1 * w64);
        }
    }

    // ======= column pooling + double-normalize + store =======
    {
        float v0, v1;
        #pragma unroll
        for (int h = 0; h < 2; ++h) {
            int o  = lane + h * 64;
            int a  = o >> 4;
            int sy = (o >> 2) & 3;
            int sx = o & 3;
            float s = 0.0f;
            #pragma unroll 2
            for (int k = 0; k < 26; ++k) {
                int c = sx * 16 - 6 + k;
                if ((unsigned)c <= 64u) {
                    float wc = (13.0f - fabsf((float)k - 12.5f)) * (1.0f / 13.0f);
                    s = fmaf(wc, part[c * PSTR + sy * 8 + a], s);
                }
            }
            if (h == 0) v0 = s; else v1 = s;
        }
        float ss = v0 * v0 + v1 * v1;
        #pragma unroll
        for (int off = 32; off > 0; off >>= 1) ss += __shfl_xor(ss, off, 64);
        float sc = 1.0f / fmaxf(sqrtf(ss), 1e-12f);
        v0 = fminf(fmaxf(v0 * sc, 0.0f), 0.2f);
        v1 = fminf(fmaxf(v1 * sc, 0.0f), 0.2f);
        ss = v0 * v0 + v1 * v1;
        #pragma unroll
        for (int off = 32; off > 0; off >>= 1) ss += __shfl_xor(ss, off, 64);
        sc = 1.0f / fmaxf(sqrtf(ss), 1e-12f);
        out[(size_t)m * 128 + lane]      = v0 * sc;
        out[(size_t)m * 128 + lane + 64] = v1 * sc;
    }
}

extern "C" void kernel_launch(void* const* d_in, const int* in_sizes, int n_in,
                              void* d_out, int out_size, void* d_ws, size_t ws_size,
                              hipStream_t stream) {
    const float* in = (const float*)d_in[0];
    float* out = (float*)d_out;
    sift_kernel<<<3072, 64, 0, stream>>>(in, out);
}